// Round 9
// baseline (49.670 us; speedup 1.0000x reference)
//
#include <hip/hip_runtime.h>

#define N_STATES 12
#define MAX_OBS 50
#define TABLE_SIZE (N_STATES * MAX_OBS)  // 600 bins
#define SUM_BLOCKS 512
#define SUM_THREADS 512

// d_ws layout: [0..SUM_BLOCKS) block partials

// Fused kernel: per-block 600-bin LDS histogram of (state,obs) [R7's exact
// hot loop: load -> addr -> ds_add fire-and-forget, no lgkm wait], then each
// block computes the log-prob table INLINE (600 bins / 512 thr ~= 1-2 bins,
// double precision, ~1us once per block) and dots it with its counts.
// Eliminates the build_table dispatch and the global table round-trip.
__global__ void __launch_bounds__(SUM_THREADS, 4) nb_hist_kernel(const float* __restrict__ obs,
                                                                 const int* __restrict__ states,
                                                                 const float* __restrict__ state_means,
                                                                 const float* __restrict__ state_phis,
                                                                 float* __restrict__ partials,
                                                                 int n) {
    __shared__ unsigned int hist[TABLE_SIZE];
    for (int i = threadIdx.x; i < TABLE_SIZE; i += blockDim.x)
        hist[i] = 0u;
    __syncthreads();

    const int tid = blockIdx.x * blockDim.x + threadIdx.x;
    const int nthreads = gridDim.x * blockDim.x;
    const int n4 = n >> 2;
    const float4* __restrict__ obs4 = (const float4*)obs;
    const int4*  __restrict__ st4  = (const int4*)states;

    #pragma unroll 4
    for (int i = tid; i < n4; i += nthreads) {
        float4 o = obs4[i];
        int4   s = st4[i];
        atomicAdd(&hist[s.x * MAX_OBS + (int)o.x], 1u);
        atomicAdd(&hist[s.y * MAX_OBS + (int)o.y], 1u);
        atomicAdd(&hist[s.z * MAX_OBS + (int)o.z], 1u);
        atomicAdd(&hist[s.w * MAX_OBS + (int)o.w], 1u);
    }
    for (int i = (n4 << 2) + tid; i < n; i += nthreads)
        atomicAdd(&hist[states[i] * MAX_OBS + (int)obs[i]], 1u);
    __syncthreads();

    // Inline table + dot. Counts < 2^24 are exact in float.
    // lp(s,o) = m*log(phi/(m+phi)) + o*log(m/(m+phi))
    //         + lgamma(o+m) - lgamma(o+1) - lgamma(m)
    float acc = 0.0f;
    for (int i = threadIdx.x; i < TABLE_SIZE; i += blockDim.x) {
        unsigned int c = hist[i];
        int s = i / MAX_OBS;
        int o = i - s * MAX_OBS;
        double m  = (double)state_means[s];
        double ph = (double)state_phis[s];
        double ob = (double)o;
        double log_denom = log(m + ph);
        double lp = m * (log(ph) - log_denom) + ob * (log(m) - log_denom)
                  + lgamma(ob + m) - lgamma(ob + 1.0) - lgamma(m);
        acc += (float)c * (float)lp;
    }

    // wave64 butterfly reduce
    #pragma unroll
    for (int off = 32; off > 0; off >>= 1)
        acc += __shfl_down(acc, off, 64);

    __shared__ float wsum[SUM_THREADS / 64];
    const int lane = threadIdx.x & 63;
    const int wid  = threadIdx.x >> 6;
    if (lane == 0) wsum[wid] = acc;
    __syncthreads();
    if (threadIdx.x == 0) {
        float s = 0.0f;
        #pragma unroll
        for (int w = 0; w < SUM_THREADS / 64; ++w) s += wsum[w];
        partials[blockIdx.x] = s;
    }
}

// Final reduce: SUM_BLOCKS partials -> *out. Single block, single writer of
// d_out (so no pre-zeroing of the poisoned output is needed).
__global__ void __launch_bounds__(SUM_BLOCKS) final_reduce_kernel(const float* __restrict__ partials,
                                                                  float* __restrict__ out) {
    float acc = partials[threadIdx.x];  // blockDim.x == SUM_BLOCKS
    #pragma unroll
    for (int off = 32; off > 0; off >>= 1)
        acc += __shfl_down(acc, off, 64);
    __shared__ float wsum[SUM_BLOCKS / 64];
    const int lane = threadIdx.x & 63;
    const int wid  = threadIdx.x >> 6;
    if (lane == 0) wsum[wid] = acc;
    __syncthreads();
    if (threadIdx.x == 0) {
        float s = 0.0f;
        #pragma unroll
        for (int w = 0; w < SUM_BLOCKS / 64; ++w) s += wsum[w];
        *out = s;
    }
}

extern "C" void kernel_launch(void* const* d_in, const int* in_sizes, int n_in,
                              void* d_out, int out_size, void* d_ws, size_t ws_size,
                              hipStream_t stream) {
    const float* obs         = (const float*)d_in[0];
    const int*   states      = (const int*)d_in[1];
    const float* state_means = (const float*)d_in[2];
    const float* state_phis  = (const float*)d_in[3];
    float* out      = (float*)d_out;
    float* partials = (float*)d_ws;
    const int n = in_sizes[0];

    nb_hist_kernel<<<dim3(SUM_BLOCKS), dim3(SUM_THREADS), 0, stream>>>(
        obs, states, state_means, state_phis, partials, n);

    final_reduce_kernel<<<dim3(1), dim3(SUM_BLOCKS), 0, stream>>>(partials, out);
}

// Round 10
// 33.107 us; speedup vs baseline: 1.5003x; 1.5003x over previous
//
#include <hip/hip_runtime.h>

#define N_STATES 12
#define MAX_OBS 50
#define TABLE_SIZE (N_STATES * MAX_OBS)  // 600 bins
#define SUM_BLOCKS 512
#define SUM_THREADS 512

// d_ws layout: [0..600) table

// Kernel 1: 600-entry log-prob table in double precision; also zeroes *out
// (stream-ordered before the hist kernel's atomicAdds; d_out is poisoned
// before timing and never re-poisoned between replays).
// lp(s,o) = m*log(phi/(m+phi)) + o*log(m/(m+phi)) + lgamma(o+m) - lgamma(o+1) - lgamma(m)
__global__ void build_table_kernel(const float* __restrict__ state_means,
                                   const float* __restrict__ state_phis,
                                   float* __restrict__ table,
                                   float* __restrict__ out) {
    if (blockIdx.x == 0 && threadIdx.x == 0) *out = 0.0f;
    int t = blockIdx.x * blockDim.x + threadIdx.x;
    if (t >= TABLE_SIZE) return;
    int s = t / MAX_OBS;
    int o = t - s * MAX_OBS;
    double m  = (double)state_means[s];
    double ph = (double)state_phis[s];
    double ob = (double)o;
    double log_denom = log(m + ph);
    double lp = m * (log(ph) - log_denom) + ob * (log(m) - log_denom)
              + lgamma(ob + m) - lgamma(ob + 1.0) - lgamma(m);
    table[t] = (float)lp;
}

// Kernel 2 (R7's proven hot loop, unchanged): per-block 600-bin LDS histogram
// via fire-and-forget ds_add (no lgkm wait in the hot loop), then dot with
// the global table (2.4 KB, L2-hot) and ONE atomicAdd per block to *out.
// 512 staggered same-address atomics are ~ns each at block-retire spread;
// R1-R6 established global atomics were never this kernel's floor.
__global__ void __launch_bounds__(SUM_THREADS, 4) nb_hist_kernel(const float* __restrict__ obs,
                                                                 const int* __restrict__ states,
                                                                 const float* __restrict__ table,
                                                                 float* __restrict__ out,
                                                                 int n) {
    __shared__ unsigned int hist[TABLE_SIZE];
    for (int i = threadIdx.x; i < TABLE_SIZE; i += blockDim.x)
        hist[i] = 0u;
    __syncthreads();

    const int tid = blockIdx.x * blockDim.x + threadIdx.x;
    const int nthreads = gridDim.x * blockDim.x;
    const int n4 = n >> 2;
    const float4* __restrict__ obs4 = (const float4*)obs;
    const int4*  __restrict__ st4  = (const int4*)states;

    #pragma unroll 4
    for (int i = tid; i < n4; i += nthreads) {
        float4 o = obs4[i];
        int4   s = st4[i];
        atomicAdd(&hist[s.x * MAX_OBS + (int)o.x], 1u);
        atomicAdd(&hist[s.y * MAX_OBS + (int)o.y], 1u);
        atomicAdd(&hist[s.z * MAX_OBS + (int)o.z], 1u);
        atomicAdd(&hist[s.w * MAX_OBS + (int)o.w], 1u);
    }
    for (int i = (n4 << 2) + tid; i < n; i += nthreads)
        atomicAdd(&hist[states[i] * MAX_OBS + (int)obs[i]], 1u);
    __syncthreads();

    // Dot counts with table (counts < 2^24, exact in float).
    float acc = 0.0f;
    for (int i = threadIdx.x; i < TABLE_SIZE; i += blockDim.x)
        acc += (float)hist[i] * table[i];

    // wave64 butterfly reduce
    #pragma unroll
    for (int off = 32; off > 0; off >>= 1)
        acc += __shfl_down(acc, off, 64);

    __shared__ float wsum[SUM_THREADS / 64];
    const int lane = threadIdx.x & 63;
    const int wid  = threadIdx.x >> 6;
    if (lane == 0) wsum[wid] = acc;
    __syncthreads();
    if (threadIdx.x == 0) {
        float s = 0.0f;
        #pragma unroll
        for (int w = 0; w < SUM_THREADS / 64; ++w) s += wsum[w];
        atomicAdd(out, s);
    }
}

extern "C" void kernel_launch(void* const* d_in, const int* in_sizes, int n_in,
                              void* d_out, int out_size, void* d_ws, size_t ws_size,
                              hipStream_t stream) {
    const float* obs         = (const float*)d_in[0];
    const int*   states      = (const int*)d_in[1];
    const float* state_means = (const float*)d_in[2];
    const float* state_phis  = (const float*)d_in[3];
    float* out   = (float*)d_out;
    float* table = (float*)d_ws;
    const int n = in_sizes[0];

    build_table_kernel<<<dim3((TABLE_SIZE + 255) / 256), dim3(256), 0, stream>>>(
        state_means, state_phis, table, out);

    nb_hist_kernel<<<dim3(SUM_BLOCKS), dim3(SUM_THREADS), 0, stream>>>(
        obs, states, table, out, n);
}

// Round 11
// 32.048 us; speedup vs baseline: 1.5499x; 1.0330x over previous
//
#include <hip/hip_runtime.h>

#define N_STATES 12
#define MAX_OBS 50
#define TABLE_SIZE (N_STATES * MAX_OBS)  // 600 bins
#define SUM_BLOCKS 512
#define SUM_THREADS 512

// d_ws layout: [0..600) table | [600..600+SUM_BLOCKS) block partials

// Kernel 1: 600-entry log-prob table in double precision.
// lp(s,o) = m*log(phi/(m+phi)) + o*log(m/(m+phi)) + lgamma(o+m) - lgamma(o+1) - lgamma(m)
__global__ void build_table_kernel(const float* __restrict__ state_means,
                                   const float* __restrict__ state_phis,
                                   float* __restrict__ table) {
    int t = blockIdx.x * blockDim.x + threadIdx.x;
    if (t >= TABLE_SIZE) return;
    int s = t / MAX_OBS;
    int o = t - s * MAX_OBS;
    double m  = (double)state_means[s];
    double ph = (double)state_phis[s];
    double ob = (double)o;
    double log_denom = log(m + ph);
    double lp = m * (log(ph) - log_denom) + ob * (log(m) - log_denom)
              + lgamma(ob + m) - lgamma(ob + 1.0) - lgamma(m);
    table[t] = (float)lp;
}

// Kernel 2 (R7 proven best): per-block 600-bin LDS histogram via
// fire-and-forget ds_add (no lgkm wait in the hot loop: the only per-element
// chain is load -> addr -> atomic-issue), then one dot with the table and a
// per-block partial store. 512x512 = 2 blocks/CU; R8 showed higher occupancy
// and sub-histogram splitting are both null -> this is the structural rate.
__global__ void __launch_bounds__(SUM_THREADS, 4) nb_hist_kernel(const float* __restrict__ obs,
                                                                 const int* __restrict__ states,
                                                                 const float* __restrict__ table,
                                                                 float* __restrict__ partials,
                                                                 int n) {
    __shared__ unsigned int hist[TABLE_SIZE];
    for (int i = threadIdx.x; i < TABLE_SIZE; i += blockDim.x)
        hist[i] = 0u;
    __syncthreads();

    const int tid = blockIdx.x * blockDim.x + threadIdx.x;
    const int nthreads = gridDim.x * blockDim.x;
    const int n4 = n >> 2;
    const float4* __restrict__ obs4 = (const float4*)obs;
    const int4*  __restrict__ st4  = (const int4*)states;

    #pragma unroll 4
    for (int i = tid; i < n4; i += nthreads) {
        float4 o = obs4[i];
        int4   s = st4[i];
        atomicAdd(&hist[s.x * MAX_OBS + (int)o.x], 1u);
        atomicAdd(&hist[s.y * MAX_OBS + (int)o.y], 1u);
        atomicAdd(&hist[s.z * MAX_OBS + (int)o.z], 1u);
        atomicAdd(&hist[s.w * MAX_OBS + (int)o.w], 1u);
    }
    for (int i = (n4 << 2) + tid; i < n; i += nthreads)
        atomicAdd(&hist[states[i] * MAX_OBS + (int)obs[i]], 1u);
    __syncthreads();

    // Dot counts with table (counts < 2^24, exact in float).
    float acc = 0.0f;
    for (int i = threadIdx.x; i < TABLE_SIZE; i += blockDim.x)
        acc += (float)hist[i] * table[i];

    // wave64 butterfly reduce
    #pragma unroll
    for (int off = 32; off > 0; off >>= 1)
        acc += __shfl_down(acc, off, 64);

    __shared__ float wsum[SUM_THREADS / 64];
    const int lane = threadIdx.x & 63;
    const int wid  = threadIdx.x >> 6;
    if (lane == 0) wsum[wid] = acc;
    __syncthreads();
    if (threadIdx.x == 0) {
        float s = 0.0f;
        #pragma unroll
        for (int w = 0; w < SUM_THREADS / 64; ++w) s += wsum[w];
        partials[blockIdx.x] = s;
    }
}

// Kernel 3: reduce SUM_BLOCKS partials -> *out. Single block, single writer
// of d_out (no pre-zeroing of the poisoned output needed).
__global__ void __launch_bounds__(SUM_BLOCKS) final_reduce_kernel(const float* __restrict__ partials,
                                                                  float* __restrict__ out) {
    float acc = partials[threadIdx.x];  // blockDim.x == SUM_BLOCKS
    #pragma unroll
    for (int off = 32; off > 0; off >>= 1)
        acc += __shfl_down(acc, off, 64);
    __shared__ float wsum[SUM_BLOCKS / 64];
    const int lane = threadIdx.x & 63;
    const int wid  = threadIdx.x >> 6;
    if (lane == 0) wsum[wid] = acc;
    __syncthreads();
    if (threadIdx.x == 0) {
        float s = 0.0f;
        #pragma unroll
        for (int w = 0; w < SUM_BLOCKS / 64; ++w) s += wsum[w];
        *out = s;
    }
}

extern "C" void kernel_launch(void* const* d_in, const int* in_sizes, int n_in,
                              void* d_out, int out_size, void* d_ws, size_t ws_size,
                              hipStream_t stream) {
    const float* obs         = (const float*)d_in[0];
    const int*   states      = (const int*)d_in[1];
    const float* state_means = (const float*)d_in[2];
    const float* state_phis  = (const float*)d_in[3];
    float* out      = (float*)d_out;
    float* table    = (float*)d_ws;
    float* partials = table + TABLE_SIZE;
    const int n = in_sizes[0];

    build_table_kernel<<<dim3((TABLE_SIZE + 255) / 256), dim3(256), 0, stream>>>(
        state_means, state_phis, table);

    nb_hist_kernel<<<dim3(SUM_BLOCKS), dim3(SUM_THREADS), 0, stream>>>(
        obs, states, table, partials, n);

    final_reduce_kernel<<<dim3(1), dim3(SUM_BLOCKS), 0, stream>>>(partials, out);
}